// Round 6
// baseline (70.431 us; speedup 1.0000x reference)
//
#include <hip/hip_runtime.h>
#include <cstddef>

#define NB 8
#define NN 1024
#define NF 32
#define NIDX 4
#define TIR 16          // i-rows per block
#define WIR 4           // i-rows per wave
#define JC 4            // j-chunks (grid z)
#define JCH 256
#define NJT 4           // 64-wide j-tiles per chunk

// ---- ws layout (float offsets) ----
#define OFF_ROW   0u
#define OFF_COLP  8192u          // [64][8192]
#define OFF_DINV  532480u
#define OFF_P     540672u        // [8192][8]
#define OFF_R     606208u
#define OFF_WP    671744u        // [65536] atomic accumulator w = M r

#if __has_builtin(__builtin_amdgcn_sinf)
#define FSIN(x) __builtin_amdgcn_sinf(x)   // sin(2*pi*x), |x|<0.5 here
#define FCOS(x) __builtin_amdgcn_cosf(x)
#else
#define FSIN(x) __sinf((x) * 6.283185307179586f)
#define FCOS(x) __cosf((x) * 6.283185307179586f)
#endif

// Fused row+col sums of adj (one read) + zero the wpart atomic accumulator.
__global__ __launch_bounds__(512) void k_sums(const float* __restrict__ adj,
                                              float* __restrict__ rowsum,
                                              float* __restrict__ colpart,
                                              float* __restrict__ wpart) {
  int b = blockIdx.x, strip = blockIdx.y;
  int t = threadIdx.x, lane = t & 63, w = t >> 6;
  { int zid = blockIdx.x*64 + blockIdx.y;            // 512 blocks x 128 = 65536
    if (t < 128) wpart[zid*128 + t] = 0.f; }
  float colreg[16];
  #pragma unroll
  for (int i = 0; i < 16; ++i) colreg[i] = 0.f;
  int r0 = strip*16 + w*2;
  #pragma unroll
  for (int rr = 0; rr < 2; ++rr) {
    const float4* row4 = reinterpret_cast<const float4*>(adj + ((size_t)b*NN + r0 + rr)*NN);
    float rs = 0.f;
    #pragma unroll
    for (int cq = 0; cq < 4; ++cq) {
      float4 v = row4[cq*64 + lane];
      colreg[cq*4+0] += v.x; colreg[cq*4+1] += v.y;
      colreg[cq*4+2] += v.z; colreg[cq*4+3] += v.w;
      rs += (v.x + v.y) + (v.z + v.w);
    }
    #pragma unroll
    for (int o = 32; o > 0; o >>= 1) rs += __shfl_xor(rs, o);
    if (lane == 0) rowsum[b*NN + r0 + rr] = rs;
  }
  __shared__ float cacc[8][NN];
  #pragma unroll
  for (int cq = 0; cq < 4; ++cq)
    #pragma unroll
    for (int x = 0; x < 4; ++x) cacc[w][cq*256 + lane*4 + x] = colreg[cq*4+x];
  __syncthreads();
  for (int c = t; c < NN; c += 512) {
    float s = 0.f;
    #pragma unroll
    for (int ww = 0; ww < 8; ++ww) s += cacc[ww][c];
    colpart[(size_t)strip*(NB*NN) + b*NN + c] = s;
  }
}

// dinv + feature contractions; also pre-initializes out = svec + bias.
// p=(w1+2w2).X, r=dinv*(-2w2).X, out=(w0+w2).X + bias
__global__ __launch_bounds__(256) void k_prep(const float* __restrict__ Xr, const float* __restrict__ Xi,
                       const float* __restrict__ weight,
                       const float* __restrict__ rowsum, const float* __restrict__ colpart,
                       const float* __restrict__ bias,
                       float* __restrict__ dinv,
                       float* __restrict__ pvec, float* __restrict__ rvec,
                       float* __restrict__ out) {
  __shared__ float wsm[NIDX*3*NF];
  int t = threadIdx.x;
  for (int e = t; e < NIDX*3*NF; e += 256) wsm[e] = weight[e];
  __syncthreads();
  int gid = blockIdx.x*256 + t;
  float cs = 0.f;
  for (int k = 0; k < 64; ++k) cs += colpart[(size_t)k*(NB*NN) + gid];
  float D = 0.5f*(rowsum[gid] + cs);
  float di = (D > 0.f) ? (1.0f / sqrtf(D)) : 0.f;
  dinv[gid] = di;
  const float* xr = Xr + (size_t)gid*NF;
  const float* xi = Xi + (size_t)gid*NF;
  float acc[NIDX][3][2];
  #pragma unroll
  for (int x = 0; x < NIDX; ++x)
    #pragma unroll
    for (int v = 0; v < 3; ++v) { acc[x][v][0] = 0.f; acc[x][v][1] = 0.f; }
  for (int f = 0; f < NF; ++f) {
    float xrf = xr[f], xif = xi[f];
    #pragma unroll
    for (int x = 0; x < NIDX; ++x) {
      float w0 = wsm[x*96 + f], w1 = wsm[x*96 + 32 + f], w2 = wsm[x*96 + 64 + f];
      float av = w0 + w2, bv = w1 + 2.f*w2, cv = -2.f*w2;
      acc[x][0][0] += av*xrf; acc[x][0][1] += av*xif;
      acc[x][1][0] += bv*xrf; acc[x][1][1] += bv*xif;
      acc[x][2][0] += cv*xrf; acc[x][2][1] += cv*xif;
    }
  }
  #pragma unroll
  for (int x = 0; x < NIDX; ++x) {
    size_t o = (size_t)gid*8 + x*2;
    pvec[o] = acc[x][1][0];      pvec[o+1] = acc[x][1][1];
    rvec[o] = di*acc[x][2][0];   rvec[o+1] = di*acc[x][2][1];
    out[gid*4 + x]         = acc[x][0][0] + bias[x];   // real part
    out[32768 + gid*4 + x] = acc[x][0][1];             // imag part
  }
}

// M-application: lanes on j (v loaded once per 64-j tile, reused across 16 i-rows),
// i wave-uniform. Wave owns 4 i-rows (acc = 32 VGPR, below the 128 cliff).
// MODE 0: vin=rvec (dinv_j prefolded) -> atomicAdd into wpart.
// MODE 1: v_j = dinv_j*(pvec_j + wpart_j) inline -> atomicAdd into out.
template<int MODE>
__global__ __launch_bounds__(256, 4) void k_pass(const float* __restrict__ adj,
                                                 const float* __restrict__ dinv,
                                                 const float* __restrict__ vin,
                                                 const float* __restrict__ pvec,
                                                 const float* __restrict__ wpart,
                                                 float* __restrict__ outacc) {
  __shared__ float Tjs[64][17];        // adj[j][i] tile (64j x 16i), 2-way reads (free)
  __shared__ float red[4][WIR*72];
  int b = blockIdx.y, i0 = blockIdx.x*TIR, zc = blockIdx.z;
  int t = threadIdx.x, lane = t & 63, w = t >> 6;
  int wu = __builtin_amdgcn_readfirstlane(w);
  float accr[WIR][NIDX], acci[WIR][NIDX];
  #pragma unroll
  for (int s = 0; s < WIR; ++s)
    #pragma unroll
    for (int x = 0; x < NIDX; ++x) { accr[s][x] = 0.f; acci[s][x] = 0.f; }

  for (int jt = 0; jt < NJT; ++jt) {
    int j0 = zc*JCH + jt*64;
    __syncthreads();                                   // prev-tile reads done
    {
      int jj = t >> 2, i4 = (t & 3) << 2;              // 64 rows x 4 float4
      float4 vv = *reinterpret_cast<const float4*>(adj + ((size_t)b*NN + j0 + jj)*NN + i0 + i4);
      float* dst = &Tjs[jj][i4];
      dst[0] = vv.x; dst[1] = vv.y; dst[2] = vv.z; dst[3] = vv.w;
    }
    int gj = b*NN + j0 + lane;
    float vr[NIDX], vi[NIDX];
    if constexpr (MODE == 0) {
      const float4* vb = reinterpret_cast<const float4*>(vin + (size_t)gj*8);
      float4 a = vb[0], c = vb[1];
      vr[0]=a.x; vi[0]=a.y; vr[1]=a.z; vi[1]=a.w;
      vr[2]=c.x; vi[2]=c.y; vr[3]=c.z; vi[3]=c.w;
    } else {
      const float4* pb = reinterpret_cast<const float4*>(pvec + (size_t)gj*8);
      const float4* wb = reinterpret_cast<const float4*>(wpart + (size_t)gj*8);
      float4 p0 = pb[0], p1 = pb[1], w0 = wb[0], w1 = wb[1];
      float dj = dinv[gj];
      vr[0]=dj*(p0.x+w0.x); vi[0]=dj*(p0.y+w0.y);
      vr[1]=dj*(p0.z+w0.z); vi[1]=dj*(p0.w+w0.w);
      vr[2]=dj*(p1.x+w1.x); vi[2]=dj*(p1.y+w1.y);
      vr[3]=dj*(p1.z+w1.z); vi[3]=dj*(p1.w+w1.w);
    }
    __syncthreads();                                   // tile visible
    const float* arb = adj + ((size_t)b*NN + i0 + wu*WIR)*NN + j0 + lane;
    #pragma unroll
    for (int s = 0; s < WIR; ++s) {
      float ar = arb[(size_t)s*NN];                    // a[i][j], coalesced
      float ac = Tjs[lane][wu*WIR + s];                // a[j][i]
      float dd = ar - ac, sm = ar + ac;
      float snv[NIDX], csv[NIDX];
      float u4 = 0.25f*dd;                             // q=1/4 (revolutions)
      snv[2] = FSIN(u4); csv[2] = FCOS(u4);
      float s4sq = snv[2]*snv[2];
      csv[0] = 1.f - 2.f*s4sq;                         // q=1/2 by double-angle (exact)
      snv[0] = 2.f*snv[2]*csv[2];
      float u1 = (1.f/3.f)*dd;
      snv[1] = FSIN(u1); csv[1] = FCOS(u1);
      float u3 = 0.2f*dd;
      snv[3] = FSIN(u3); csv[3] = FCOS(u3);
      #pragma unroll
      for (int x = 0; x < NIDX; ++x) {
        float A = sm*csv[x], B = sm*snv[x];
        accr[s][x] += A*vr[x] - B*vi[x];
        acci[s][x] += A*vi[x] + B*vr[x];
      }
    }
  }

  // in-wave 8x8 transpose-reduce per s (verified R4): lane ends with slot (lane&7)
  // summed over its 8-lane group.
  bool b1 = (lane & 1), b2 = (lane & 2), b4 = (lane & 4);
  #pragma unroll
  for (int s = 0; s < WIR; ++s) {
    float v0 = accr[s][0], v1 = acci[s][0], v2 = accr[s][1], v3 = acci[s][1];
    float v4 = accr[s][2], v5 = acci[s][2], v6 = accr[s][3], v7 = acci[s][3];
    float k0 = b1 ? v1 : v0, s0 = b1 ? v0 : v1;
    float k1 = b1 ? v3 : v2, s1 = b1 ? v2 : v3;
    float k2 = b1 ? v5 : v4, s2 = b1 ? v4 : v5;
    float k3 = b1 ? v7 : v6, s3 = b1 ? v6 : v7;
    v0 = k0 + __shfl_xor(s0, 1);
    v1 = k1 + __shfl_xor(s1, 1);
    v2 = k2 + __shfl_xor(s2, 1);
    v3 = k3 + __shfl_xor(s3, 1);
    k0 = b2 ? v1 : v0; s0 = b2 ? v0 : v1;
    k1 = b2 ? v3 : v2; s1 = b2 ? v2 : v3;
    v0 = k0 + __shfl_xor(s0, 2);
    v1 = k1 + __shfl_xor(s1, 2);
    k0 = b4 ? v1 : v0; s0 = b4 ? v0 : v1;
    v0 = k0 + __shfl_xor(s0, 4);
    red[w][s*72 + (lane & 7)*9 + (lane >> 3)] = v0;
  }
  __syncthreads();
  if (t < TIR*8) {
    int row = t >> 3, slot = t & 7;                    // row 0..15, slot 0..7
    float sum = 0.f;
    #pragma unroll
    for (int g = 0; g < 8; ++g) sum += red[row >> 2][(row & 3)*72 + slot*9 + g];
    int gi = b*NN + i0 + row;
    float val = sum * 0.5f * dinv[gi];
    if constexpr (MODE == 0) atomicAdd(&outacc[(size_t)gi*8 + slot], val);
    else atomicAdd(&outacc[(slot & 1)*32768 + gi*4 + (slot >> 1)], val);
  }
}

extern "C" void kernel_launch(void* const* d_in, const int* in_sizes, int n_in,
                              void* d_out, int out_size, void* d_ws, size_t ws_size,
                              hipStream_t stream) {
  (void)in_sizes; (void)n_in; (void)out_size; (void)ws_size;
  const float* Xr     = (const float*)d_in[0];
  const float* Xi     = (const float*)d_in[1];
  const float* adj    = (const float*)d_in[2];
  const float* weight = (const float*)d_in[3];
  const float* bias   = (const float*)d_in[4];
  float* ws = (float*)d_ws;
  float* rowsum  = ws + OFF_ROW;
  float* colpart = ws + OFF_COLP;
  float* dinv    = ws + OFF_DINV;
  float* pvec    = ws + OFF_P;
  float* rvec    = ws + OFF_R;
  float* wpart   = ws + OFF_WP;
  float* out = (float*)d_out;

  k_sums<<<dim3(NB, 64), 512, 0, stream>>>(adj, rowsum, colpart, wpart);
  k_prep<<<dim3(NB*NN/256), 256, 0, stream>>>(Xr, Xi, weight, rowsum, colpart, bias,
                                              dinv, pvec, rvec, out);
  k_pass<0><<<dim3(NN/TIR, NB, JC), 256, 0, stream>>>(adj, dinv, rvec, pvec, wpart, wpart);
  k_pass<1><<<dim3(NN/TIR, NB, JC), 256, 0, stream>>>(adj, dinv, rvec, pvec, wpart, out);
}

// Round 8
// 53.406 us; speedup vs baseline: 1.3188x; 1.3188x over previous
//
#include <hip/hip_runtime.h>
#include <cstddef>

#define NB 8
#define NN 1024
#define NF 32
#define NIDX 4
#define JC 4            // j-chunks per pass (grid z)
#define JCH 256         // j's per chunk
#define NJT 4           // 64-wide j-tiles per chunk

// ---- ws layout (float offsets) ----
#define OFF_ROW   0u
#define OFF_COLP  8192u          // [64][8192]
#define OFF_DINV  532480u
#define OFF_S     540672u        // [8192][8]
#define OFF_P     606208u
#define OFF_R     671744u
#define OFF_WP    737280u        // [JC][65536]

#if __has_builtin(__builtin_amdgcn_sinf)
#define FSIN(x) __builtin_amdgcn_sinf(x)   // sin(2*pi*x), |x|<0.5 here
#define FCOS(x) __builtin_amdgcn_cosf(x)
#else
#define FSIN(x) __sinf((x) * 6.283185307179586f)
#define FCOS(x) __cosf((x) * 6.283185307179586f)
#endif

// Fused row+col sums of adj (one read) + zero d_out for pass2's atomics.
// grid (NB, 64): linear bid % 8 == b -> XCD b's L2 ends up holding adj[b].
__global__ __launch_bounds__(512) void k_sums(const float* __restrict__ adj,
                                              float* __restrict__ rowsum,
                                              float* __restrict__ colpart,
                                              float* __restrict__ out) {
  int b = blockIdx.x, strip = blockIdx.y;
  int t = threadIdx.x, lane = t & 63, w = t >> 6;
  { int zid = blockIdx.x*64 + blockIdx.y;            // 512 blocks x 128 = 65536
    if (t < 128) out[zid*128 + t] = 0.f; }
  float colreg[16];
  #pragma unroll
  for (int i = 0; i < 16; ++i) colreg[i] = 0.f;
  int r0 = strip*16 + w*2;
  #pragma unroll
  for (int rr = 0; rr < 2; ++rr) {
    const float4* row4 = reinterpret_cast<const float4*>(adj + ((size_t)b*NN + r0 + rr)*NN);
    float rs = 0.f;
    #pragma unroll
    for (int cq = 0; cq < 4; ++cq) {
      float4 v = row4[cq*64 + lane];
      colreg[cq*4+0] += v.x; colreg[cq*4+1] += v.y;
      colreg[cq*4+2] += v.z; colreg[cq*4+3] += v.w;
      rs += (v.x + v.y) + (v.z + v.w);
    }
    #pragma unroll
    for (int o = 32; o > 0; o >>= 1) rs += __shfl_xor(rs, o);
    if (lane == 0) rowsum[b*NN + r0 + rr] = rs;
  }
  __shared__ float cacc[8][NN];
  #pragma unroll
  for (int cq = 0; cq < 4; ++cq)
    #pragma unroll
    for (int x = 0; x < 4; ++x) cacc[w][cq*256 + lane*4 + x] = colreg[cq*4+x];
  __syncthreads();
  for (int c = t; c < NN; c += 512) {
    float s = 0.f;
    #pragma unroll
    for (int ww = 0; ww < 8; ++ww) s += cacc[ww][c];
    colpart[(size_t)strip*(NB*NN) + b*NN + c] = s;
  }
}

// dinv + the three per-node feature contractions (fused).
// s=(w0+w2).X, p=(w1+2w2).X, r=dinv*(-2w2).X
__global__ __launch_bounds__(256) void k_prep(const float* __restrict__ Xr, const float* __restrict__ Xi,
                       const float* __restrict__ weight,
                       const float* __restrict__ rowsum, const float* __restrict__ colpart,
                       float* __restrict__ dinv,
                       float* __restrict__ svec, float* __restrict__ pvec, float* __restrict__ rvec) {
  __shared__ float wsm[NIDX*3*NF];
  int t = threadIdx.x;
  for (int e = t; e < NIDX*3*NF; e += 256) wsm[e] = weight[e];
  __syncthreads();
  int gid = blockIdx.x*256 + t;
  float cs = 0.f;
  for (int k = 0; k < 64; ++k) cs += colpart[(size_t)k*(NB*NN) + gid];
  float D = 0.5f*(rowsum[gid] + cs);
  float di = (D > 0.f) ? (1.0f / sqrtf(D)) : 0.f;
  dinv[gid] = di;
  const float* xr = Xr + (size_t)gid*NF;
  const float* xi = Xi + (size_t)gid*NF;
  float acc[NIDX][3][2];
  #pragma unroll
  for (int x = 0; x < NIDX; ++x)
    #pragma unroll
    for (int v = 0; v < 3; ++v) { acc[x][v][0] = 0.f; acc[x][v][1] = 0.f; }
  for (int f = 0; f < NF; ++f) {
    float xrf = xr[f], xif = xi[f];
    #pragma unroll
    for (int x = 0; x < NIDX; ++x) {
      float w0 = wsm[x*96 + f], w1 = wsm[x*96 + 32 + f], w2 = wsm[x*96 + 64 + f];
      float av = w0 + w2, bv = w1 + 2.f*w2, cv = -2.f*w2;
      acc[x][0][0] += av*xrf; acc[x][0][1] += av*xif;
      acc[x][1][0] += bv*xrf; acc[x][1][1] += bv*xif;
      acc[x][2][0] += cv*xrf; acc[x][2][1] += cv*xif;
    }
  }
  #pragma unroll
  for (int x = 0; x < NIDX; ++x) {
    size_t o = (size_t)gid*8 + x*2;
    svec[o] = acc[x][0][0];      svec[o+1] = acc[x][0][1];
    pvec[o] = acc[x][1][0];      pvec[o+1] = acc[x][1][1];
    rvec[o] = di*acc[x][2][0];   rvec[o+1] = di*acc[x][2][1];
  }
}

// M-application, lanes on j (v reused across 64 i-steps), i wave-uniform.
// grid (NB, 16, JC): batch on fastest dim -> bid%8==b -> same XCD that staged adj[b].
// MODE 0: vin=rvec (dinv_j prefolded) -> write wpart partials.
// MODE 1: build wtot=dinv*(p+sum wpart) slice in LDS, apply M, atomicAdd into out (+svec+bias on zc==0).
template<int MODE>
__global__ __launch_bounds__(512, 4) void k_pass(const float* __restrict__ adj,
                                                 const float* __restrict__ dinv,
                                                 const float* __restrict__ vin,
                                                 float* __restrict__ wpart,
                                                 const float* __restrict__ svec,
                                                 const float* __restrict__ bias,
                                                 float* __restrict__ out) {
  __shared__ float Tjs[64][65];      // transpose tile, pad-65 -> 2-way (free)
  __shared__ float vlds[JCH][8];     // pass2 wtot slice
  __shared__ float red[8][8*72];     // per-wave [i(8)][slot(8) pad9 x grp(8)]
  int b = blockIdx.x, i0 = blockIdx.y*64, zc = blockIdx.z;
  int j0base = zc*JCH;
  int t = threadIdx.x, lane = t & 63;
  int w = t >> 6;
  int wu = __builtin_amdgcn_readfirstlane(w);

  if constexpr (MODE == 1) {
    for (int e = t; e < JCH*8; e += 512) {
      int jj = e >> 3, s = e & 7;
      size_t o = ((size_t)b*NN + j0base + jj)*8 + s;
      float v = vin[o];
      #pragma unroll
      for (int c = 0; c < JC; ++c) v += wpart[(size_t)c*65536 + o];
      vlds[jj][s] = v * dinv[b*NN + j0base + jj];
    }
  }

  float accr[8][NIDX], acci[8][NIDX];
  #pragma unroll
  for (int s = 0; s < 8; ++s)
    #pragma unroll
    for (int x = 0; x < NIDX; ++x) { accr[s][x] = 0.f; acci[s][x] = 0.f; }

  for (int jt = 0; jt < NJT; ++jt) {
    int j0 = j0base + jt*64;
    __syncthreads();                               // prev Tjs reads done / vlds ready
    #pragma unroll
    for (int m = 0; m < 2; ++m) {
      int e4 = t + 512*m;                          // 1024 float4 = 64x64 tile
      int jj = e4 >> 4, i4 = (e4 & 15) << 2;
      float4 vv = *reinterpret_cast<const float4*>(adj + ((size_t)b*NN + j0 + jj)*NN + i0 + i4);
      float* dst = &Tjs[jj][i4];
      dst[0] = vv.x; dst[1] = vv.y; dst[2] = vv.z; dst[3] = vv.w;
    }
    float vr[NIDX], vi[NIDX];
    if constexpr (MODE == 0) {
      const float4* vb = reinterpret_cast<const float4*>(vin + ((size_t)b*NN + j0 + lane)*8);
      float4 a = vb[0], c = vb[1];
      vr[0]=a.x; vi[0]=a.y; vr[1]=a.z; vi[1]=a.w;
      vr[2]=c.x; vi[2]=c.y; vr[3]=c.z; vi[3]=c.w;
    } else {
      const float4* vb = reinterpret_cast<const float4*>(&vlds[jt*64 + lane][0]);
      float4 a = vb[0], c = vb[1];
      vr[0]=a.x; vi[0]=a.y; vr[1]=a.z; vi[1]=a.w;
      vr[2]=c.x; vi[2]=c.y; vr[3]=c.z; vi[3]=c.w;
    }
    __syncthreads();                               // tile visible
    const float* arbase = adj + ((size_t)b*NN + i0 + wu*8)*NN + j0 + lane;
    #pragma unroll
    for (int s = 0; s < 8; ++s) {
      float ar = arbase[(size_t)s*NN];             // a[i][j], coalesced
      float ac = Tjs[lane][wu*8 + s];              // a[j][i], 2-way free
      float dd = ar - ac, sm = ar + ac;
      float s4 = FSIN(0.25f*dd), c4 = FCOS(0.25f*dd);      // q=1/4 seed
      float s3 = FSIN((1.f/3.f)*dd), c3 = FCOS((1.f/3.f)*dd);
      float s5 = FSIN(0.2f*dd), c5 = FCOS(0.2f*dd);
      float c2 = 1.f - 2.f*s4*s4, s2 = 2.f*s4*c4;          // q=1/2 exact double-angle
      float csv[NIDX] = {c2, c3, c4, c5};
      float snv[NIDX] = {s2, s3, s4, s5};
      #pragma unroll
      for (int x = 0; x < NIDX; ++x) {
        float A = sm*csv[x], B = sm*snv[x];
        accr[s][x] += A*vr[x] - B*vi[x];
        acci[s][x] += A*vi[x] + B*vr[x];
      }
    }
  }

  // 8x8 in-wave transpose-reduce: lane ends with slot (lane&7) of i-step s,
  // summed over its 8-lane group; static indices only.
  bool b1 = (lane & 1), b2 = (lane & 2), b4 = (lane & 4);
  #pragma unroll
  for (int s = 0; s < 8; ++s) {
    float v0 = accr[s][0], v1 = acci[s][0], v2 = accr[s][1], v3 = acci[s][1];
    float v4 = accr[s][2], v5 = acci[s][2], v6 = accr[s][3], v7 = acci[s][3];
    float k0 = b1 ? v1 : v0, s0 = b1 ? v0 : v1;
    float k1 = b1 ? v3 : v2, s1 = b1 ? v2 : v3;
    float k2 = b1 ? v5 : v4, s2 = b1 ? v4 : v5;
    float k3 = b1 ? v7 : v6, s3 = b1 ? v6 : v7;
    v0 = k0 + __shfl_xor(s0, 1);
    v1 = k1 + __shfl_xor(s1, 1);
    v2 = k2 + __shfl_xor(s2, 1);
    v3 = k3 + __shfl_xor(s3, 1);
    k0 = b2 ? v1 : v0; s0 = b2 ? v0 : v1;
    k1 = b2 ? v3 : v2; s1 = b2 ? v2 : v3;
    v0 = k0 + __shfl_xor(s0, 2);
    v1 = k1 + __shfl_xor(s1, 2);
    k0 = b4 ? v1 : v0; s0 = b4 ? v0 : v1;
    v0 = k0 + __shfl_xor(s0, 4);
    red[w][s*72 + (lane & 7)*9 + (lane >> 3)] = v0;
  }
  __syncthreads();
  {
    int iloc = w*8 + (lane >> 3), slot = lane & 7;
    float sum = 0.f;
    #pragma unroll
    for (int g = 0; g < 8; ++g) sum += red[w][(lane >> 3)*72 + slot*9 + g];
    int i = i0 + iloc;
    float val = sum * 0.5f * dinv[b*NN + i];
    if constexpr (MODE == 0) {
      wpart[(size_t)zc*65536 + ((size_t)b*NN + i)*8 + slot] = val;
    } else {
      if (zc == 0) {
        val += svec[((size_t)b*NN + i)*8 + slot];
        if ((slot & 1) == 0) val += bias[slot >> 1];
      }
      atomicAdd(&out[(slot & 1)*32768 + b*4096 + i*4 + (slot >> 1)], val);
    }
  }
}

extern "C" void kernel_launch(void* const* d_in, const int* in_sizes, int n_in,
                              void* d_out, int out_size, void* d_ws, size_t ws_size,
                              hipStream_t stream) {
  (void)in_sizes; (void)n_in; (void)out_size; (void)ws_size;
  const float* Xr     = (const float*)d_in[0];
  const float* Xi     = (const float*)d_in[1];
  const float* adj    = (const float*)d_in[2];
  const float* weight = (const float*)d_in[3];
  const float* bias   = (const float*)d_in[4];
  float* ws = (float*)d_ws;
  float* rowsum  = ws + OFF_ROW;
  float* colpart = ws + OFF_COLP;
  float* dinv    = ws + OFF_DINV;
  float* svec    = ws + OFF_S;
  float* pvec    = ws + OFF_P;
  float* rvec    = ws + OFF_R;
  float* wpart   = ws + OFF_WP;
  float* out = (float*)d_out;

  k_sums<<<dim3(NB, 64), 512, 0, stream>>>(adj, rowsum, colpart, out);
  k_prep<<<dim3(NB*NN/256), 256, 0, stream>>>(Xr, Xi, weight, rowsum, colpart, dinv, svec, pvec, rvec);
  k_pass<0><<<dim3(NB, NN/64, JC), 512, 0, stream>>>(adj, dinv, rvec, wpart, svec, bias, out);
  k_pass<1><<<dim3(NB, NN/64, JC), 512, 0, stream>>>(adj, dinv, pvec, wpart, svec, bias, out);
}